// Round 2
// baseline (11415.968 us; speedup 1.0000x reference)
//
#include <hip/hip_runtime.h>

#define HID 128
#define EA_DIM 11
#define MSG_IN (2 * HID + EA_DIM)   // 267
#define G 4

__device__ __forceinline__ float siluf(float x) { return x / (1.f + __expf(-x)); }

// ---------------- encoder: h = silu(silu(x@W1+b1)@W2+b2) ----------------
__global__ __launch_bounds__(128) void encoder_kernel(
    const float* __restrict__ x, const float* __restrict__ W1, const float* __restrict__ b1,
    const float* __restrict__ W2, const float* __restrict__ b2,
    float* __restrict__ h)
{
    int i = blockIdx.x, j = threadIdx.x;
    __shared__ float xs[9];
    __shared__ float t1[HID];
    if (j < 9) xs[j] = x[(size_t)i * 9 + j];
    __syncthreads();
    float acc = b1[j];
    #pragma unroll
    for (int k = 0; k < 9; ++k) acc = fmaf(xs[k], W1[k * HID + j], acc);
    t1[j] = siluf(acc);
    __syncthreads();
    float acc2 = b2[j];
    #pragma unroll 8
    for (int k = 0; k < HID; ++k) acc2 = fmaf(t1[k], W2[k * HID + j], acc2);
    h[(size_t)i * HID + j] = siluf(acc2);
}

// ---- message: m = silu([h_s,h_d,ea]@W1+b1)@W2+b2 ; atomic agg[dst] += m, G edges/block ----
__global__ __launch_bounds__(128) void msg_kernel(
    const float* __restrict__ h, const int* __restrict__ ei,
    const float* __restrict__ ea,
    const float* __restrict__ W1, const float* __restrict__ b1,
    const float* __restrict__ W2, const float* __restrict__ b2,
    float* __restrict__ agg, int E)
{
    int j = threadIdx.x;
    int base = blockIdx.x * G;
    __shared__ float inp[G][MSG_IN];
    __shared__ float ts[G][HID];
    int dsts[G];
    #pragma unroll
    for (int g = 0; g < G; ++g) {
        int e = base + g;
        if (e < E) {
            int s = ei[e], d = ei[E + e];
            dsts[g] = d;
            inp[g][j]       = h[(size_t)s * HID + j];
            inp[g][HID + j] = h[(size_t)d * HID + j];
            if (j < EA_DIM) inp[g][2 * HID + j] = ea[(size_t)e * EA_DIM + j];
        } else {
            dsts[g] = -1;
            inp[g][j] = 0.f; inp[g][HID + j] = 0.f;
            if (j < EA_DIM) inp[g][2 * HID + j] = 0.f;
        }
    }
    __syncthreads();
    float b1j = b1[j];
    float acc[G];
    #pragma unroll
    for (int g = 0; g < G; ++g) acc[g] = b1j;
    #pragma unroll 4
    for (int k = 0; k < MSG_IN; ++k) {
        float w = W1[k * HID + j];
        #pragma unroll
        for (int g = 0; g < G; ++g) acc[g] = fmaf(inp[g][k], w, acc[g]);
    }
    #pragma unroll
    for (int g = 0; g < G; ++g) ts[g][j] = siluf(acc[g]);
    __syncthreads();
    float b2j = b2[j];
    float a2[G];
    #pragma unroll
    for (int g = 0; g < G; ++g) a2[g] = b2j;
    #pragma unroll 4
    for (int k = 0; k < HID; ++k) {
        float w = W2[k * HID + j];
        #pragma unroll
        for (int g = 0; g < G; ++g) a2[g] = fmaf(ts[g][k], w, a2[g]);
    }
    #pragma unroll
    for (int g = 0; g < G; ++g)
        if (dsts[g] >= 0) atomicAdd(&agg[(size_t)dsts[g] * HID + j], a2[g]);
}

// ---------------- update: h = silu(concat(h,agg)@W + b + h), G nodes/block ----------------
__global__ __launch_bounds__(128) void upd_kernel(
    float* __restrict__ h, const float* __restrict__ agg,
    const float* __restrict__ W, const float* __restrict__ b, int N)
{
    int j = threadIdx.x;
    int base = blockIdx.x * G;
    __shared__ float inp[G][2 * HID];
    float hj[G];
    #pragma unroll
    for (int g = 0; g < G; ++g) {
        int i = base + g;
        hj[g] = 0.f;
        if (i < N) {
            hj[g] = h[(size_t)i * HID + j];
            inp[g][j]       = hj[g];
            inp[g][HID + j] = agg[(size_t)i * HID + j];
        }
    }
    __syncthreads();
    float bj = b[j];
    float acc[G];
    #pragma unroll
    for (int g = 0; g < G; ++g) acc[g] = bj + hj[g];
    #pragma unroll 4
    for (int k = 0; k < 2 * HID; ++k) {
        float w = W[k * HID + j];
        #pragma unroll
        for (int g = 0; g < G; ++g) acc[g] = fmaf(inp[g][k], w, acc[g]);
    }
    #pragma unroll
    for (int g = 0; g < G; ++g) {
        int i = base + g;
        if (i < N) h[(size_t)i * HID + j] = siluf(acc[g]);
    }
}

// ---------------- edge fields decoder ----------------
// hpart[j] = b1[j] + [h_i,h_j] @ W1[1:257]  (shared across quad pts)
// per q: f1 = silu(hpart + xi*W1[0]); f2 = silu(f1@W2+b2); out = (f2@W3+b3)*mask
__global__ __launch_bounds__(64) void fields_kernel(
    const float* __restrict__ h, const int* __restrict__ conn,
    const float* __restrict__ bc,
    const float* __restrict__ W1, const float* __restrict__ b1,
    const float* __restrict__ W2, const float* __restrict__ b2,
    const float* __restrict__ W3, const float* __restrict__ b3,
    float* __restrict__ xi_out, float* __restrict__ f_out, int nq)
{
    int ec = blockIdx.x, j = threadIdx.x;   // 64 threads = 1 wave
    int n1 = conn[(size_t)ec * 2 + 0];
    int n2 = conn[(size_t)ec * 2 + 1];
    __shared__ float hs[2 * HID];
    __shared__ float ts[64];
    hs[j]       = h[(size_t)n1 * HID + j];
    hs[64 + j]  = h[(size_t)n1 * HID + 64 + j];
    hs[128 + j] = h[(size_t)n2 * HID + j];
    hs[192 + j] = h[(size_t)n2 * HID + 64 + j];
    __syncthreads();
    float hpart = b1[j];
    #pragma unroll 8
    for (int k = 0; k < 2 * HID; ++k) hpart = fmaf(hs[k], W1[(k + 1) * 64 + j], hpart);
    float w1x = W1[j];  // row 0 of W1 (xi coefficient)
    float bci = bc[n1], bcj = bc[n2];
    float b30 = b3[0], b31 = b3[1], b32 = b3[2];
    float w30 = W3[j * 3 + 0], w31 = W3[j * 3 + 1], w32 = W3[j * 3 + 2];
    float inv = (nq > 1) ? 1.f / (float)(nq - 1) : 0.f;
    for (int q = 0; q < nq; ++q) {
        float xi = (float)q * inv;
        float f1 = siluf(fmaf(xi, w1x, hpart));
        __syncthreads();
        ts[j] = f1;
        __syncthreads();
        float f2 = b2[j];
        #pragma unroll 8
        for (int k = 0; k < 64; ++k) f2 = fmaf(ts[k], W2[k * 64 + j], f2);
        f2 = siluf(f2);
        float p0 = f2 * w30, p1 = f2 * w31, p2 = f2 * w32;
        #pragma unroll
        for (int off = 32; off > 0; off >>= 1) {
            p0 += __shfl_down(p0, off);
            p1 += __shfl_down(p1, off);
            p2 += __shfl_down(p2, off);
        }
        if (j == 0) {
            float mask = (1.f - bci * (1.f - xi)) * (1.f - bcj * xi);
            size_t base = ((size_t)ec * nq + q) * 3;
            f_out[base + 0] = (p0 + b30) * mask;
            f_out[base + 1] = (p1 + b31) * mask;
            f_out[base + 2] = (p2 + b32) * mask;
            xi_out[(size_t)ec * nq + q] = xi;
        }
    }
}

// ---------------- prop passthrough ----------------
__global__ void prop_kernel(const float* __restrict__ prop, float* __restrict__ out_p, int n)
{
    int i = blockIdx.x * blockDim.x + threadIdx.x;
    if (i < n) out_p[i] = prop[i];
}

extern "C" void kernel_launch(void* const* d_in, const int* in_sizes, int n_in,
                              void* d_out, int out_size, void* d_ws, size_t ws_size,
                              hipStream_t stream) {
    const float* x     = (const float*)d_in[0];
    const int*   ei    = (const int*)d_in[1];
    const float* ea    = (const float*)d_in[2];
    const int*   conn  = (const int*)d_in[3];
    const float* bc    = (const float*)d_in[4];
    const float* prop  = (const float*)d_in[5];
    // d_in[6] = n_quad_pts (scalar; nq derived from out_size)
    const float* encW1 = (const float*)d_in[7];
    const float* encb1 = (const float*)d_in[8];
    const float* encW2 = (const float*)d_in[9];
    const float* encb2 = (const float*)d_in[10];
    const float* msgW1 = (const float*)d_in[11];
    const float* msgb1 = (const float*)d_in[12];
    const float* msgW2 = (const float*)d_in[13];
    const float* msgb2 = (const float*)d_in[14];
    const float* updW  = (const float*)d_in[15];
    const float* updb  = (const float*)d_in[16];
    const float* efW1  = (const float*)d_in[17];
    const float* efb1  = (const float*)d_in[18];
    const float* efW2  = (const float*)d_in[19];
    const float* efb2  = (const float*)d_in[20];
    const float* efW3  = (const float*)d_in[21];
    const float* efb3  = (const float*)d_in[22];

    int N  = in_sizes[0] / 9;
    int E  = in_sizes[1] / 2;
    int EC = in_sizes[5];
    int nl = in_sizes[11] / (MSG_IN * HID);
    int nq = (int)(((long long)out_size - (long long)N * HID - EC) / (4LL * EC));

    float* out    = (float*)d_out;
    float* h      = out;                       // h lives in the output's h region (fp32)
    float* out_xi = out + (size_t)N * HID;
    float* out_f  = out_xi + (size_t)EC * nq;
    float* out_p  = out_f + (size_t)EC * nq * 3;

    float* agg = (float*)d_ws;                 // N*HID fp32 scratch

    encoder_kernel<<<N, 128, 0, stream>>>(x, encW1, encb1, encW2, encb2, h);

    for (int l = 0; l < nl; ++l) {
        hipMemsetAsync(agg, 0, (size_t)N * HID * sizeof(float), stream);
        msg_kernel<<<(E + G - 1) / G, 128, 0, stream>>>(
            h, ei, ea,
            msgW1 + (size_t)l * MSG_IN * HID, msgb1 + (size_t)l * HID,
            msgW2 + (size_t)l * HID * HID,    msgb2 + (size_t)l * HID,
            agg, E);
        upd_kernel<<<(N + G - 1) / G, 128, 0, stream>>>(
            h, agg, updW + (size_t)l * 2 * HID * HID, updb + (size_t)l * HID, N);
    }

    fields_kernel<<<EC, 64, 0, stream>>>(h, conn, bc, efW1, efb1, efW2, efb2, efW3, efb3,
                                         out_xi, out_f, nq);

    prop_kernel<<<(EC + 255) / 256, 256, 0, stream>>>(prop, out_p, EC);
}

// Round 3
// 3430.736 us; speedup vs baseline: 3.3276x; 3.3276x over previous
//
#include <hip/hip_runtime.h>
#include <hip/hip_bf16.h>

#define HID 128
#define EA_DIM 11
#define MSG_IN (2 * HID + EA_DIM)   // 267
#define G 4

#define TILE_E 128
#define KCAP 272                     // layer-1 K padded to 17*16
#define KB (KCAP * 2)                // 544 bytes per LDS row
#define LDS_A1 69632                 // W1T occupies [0, 69632)
#define LDS_TOTAL 139264

typedef __attribute__((ext_vector_type(8))) short short8;
typedef __attribute__((ext_vector_type(16))) float f32x16;
typedef __attribute__((ext_vector_type(4))) float float4v;

__device__ __forceinline__ float siluf(float x) { return x / (1.f + __expf(-x)); }
__device__ __forceinline__ short f2bf(float f) {
    __hip_bfloat16 h = __float2bfloat16(f);
    return *reinterpret_cast<short*>(&h);
}

// ---------------- encoder: h = silu(silu(x@W1+b1)@W2+b2) ----------------
__global__ __launch_bounds__(128) void encoder_kernel(
    const float* __restrict__ x, const float* __restrict__ W1, const float* __restrict__ b1,
    const float* __restrict__ W2, const float* __restrict__ b2,
    float* __restrict__ h)
{
    int i = blockIdx.x, j = threadIdx.x;
    __shared__ float xs[9];
    __shared__ float t1[HID];
    if (j < 9) xs[j] = x[(size_t)i * 9 + j];
    __syncthreads();
    float acc = b1[j];
    #pragma unroll
    for (int k = 0; k < 9; ++k) acc = fmaf(xs[k], W1[k * HID + j], acc);
    t1[j] = siluf(acc);
    __syncthreads();
    float acc2 = b2[j];
    #pragma unroll 8
    for (int k = 0; k < HID; ++k) acc2 = fmaf(t1[k], W2[k * HID + j], acc2);
    h[(size_t)i * HID + j] = siluf(acc2);
}

// ---- one-time weight conversion: msgW1 -> W1T bf16 [nl][128][KCAP], msgW2 -> W2T bf16 [nl][128][128]
__global__ void convert_w_kernel(
    const float* __restrict__ msgW1, const float* __restrict__ msgW2,
    short* __restrict__ w1t, short* __restrict__ w2t, int nl)
{
    int gid = blockIdx.x * blockDim.x + threadIdx.x;
    int n1 = nl * 128 * (KCAP / 8);          // 16B chunks of w1t
    int n2 = nl * 128 * (HID / 8);
    if (gid < n1) {
        int c = gid % (KCAP / 8);
        int rem = gid / (KCAP / 8);
        int n = rem % 128, lay = rem / 128;
        short8 v;
        #pragma unroll
        for (int j = 0; j < 8; ++j) {
            int k = c * 8 + j;
            v[j] = (k < MSG_IN) ? f2bf(msgW1[(size_t)lay * MSG_IN * HID + (size_t)k * HID + n]) : (short)0;
        }
        *(short8*)(w1t + ((size_t)lay * 128 + n) * KCAP + c * 8) = v;
    } else if (gid < n1 + n2) {
        int g = gid - n1;
        int c = g % (HID / 8);
        int rem = g / (HID / 8);
        int n = rem % 128, lay = rem / 128;
        short8 v;
        #pragma unroll
        for (int j = 0; j < 8; ++j) {
            int k = c * 8 + j;
            v[j] = f2bf(msgW2[(size_t)lay * HID * HID + (size_t)k * HID + n]);
        }
        *(short8*)(w2t + ((size_t)lay * 128 + n) * HID + c * 8) = v;
    }
}

// ---------------- MFMA message kernel ----------------
// Per 128-edge tile: A = [h_src | h_dst | ea] (bf16, LDS, swizzled),
// layer1: acc1 = A @ W1 (+b1, silu) -> A2 (LDS); layer2: acc2 = A2 @ W2 (+b2);
// atomicAdd into agg[dst].
__global__ __launch_bounds__(256, 1) void msg_mfma_kernel(
    const float* __restrict__ h, const int* __restrict__ ei, const float* __restrict__ ea,
    const short* __restrict__ w1t, const float* __restrict__ b1,
    const short* __restrict__ w2t, const float* __restrict__ b2,
    float* __restrict__ agg, int E, int ntiles)
{
    extern __shared__ char smem[];          // [W1T 69632 | A1/A2 69632]
    char* sA1 = smem + LDS_A1;
    __shared__ int dsts[TILE_E];

    int tid = threadIdx.x;
    int ln = tid & 63;
    int wave = tid >> 6;
    int mhalf = wave & 1, nhalf = wave >> 1;
    int l31 = ln & 31, khalf = ln >> 5;

    // ---- stage W1T once per block (swizzled) ----
    {
        int r = tid >> 1, half = tid & 1;
        #pragma unroll
        for (int c = 0; c < 17; ++c) {
            int cc = half * 17 + c;
            short8 v = *(const short8*)(w1t + (size_t)r * KCAP + cc * 8);
            *(short8*)(smem + ((r * KB + cc * 16) ^ ((r & 7) << 4))) = v;
        }
    }

    float b1v[2], b2v[2];
    #pragma unroll
    for (int ni = 0; ni < 2; ++ni) {
        b1v[ni] = b1[nhalf * 64 + ni * 32 + l31];
        b2v[ni] = b2[nhalf * 64 + ni * 32 + l31];
    }

    #pragma unroll 1
    for (int tile = blockIdx.x; tile < ntiles; tile += gridDim.x) {
        __syncthreads();   // prior-iter LDS reads done (also covers W1T staging 1st iter)

        // ---- gather-stage A1 ----
        {
            int r = tid >> 1, half = tid & 1;
            long e = (long)tile * TILE_E + r;
            bool valid = e < E;
            int idx = 0;
            if (valid) idx = (half == 0) ? ei[e] : ei[(size_t)E + e];
            const float* hr = h + (size_t)idx * HID;
            #pragma unroll 4
            for (int c = 0; c < 16; ++c) {
                short8 v;
                if (valid) {
                    float4v f0 = *(const float4v*)(hr + c * 8);
                    float4v f1 = *(const float4v*)(hr + c * 8 + 4);
                    #pragma unroll
                    for (int j = 0; j < 4; ++j) { v[j] = f2bf(f0[j]); v[4 + j] = f2bf(f1[j]); }
                } else {
                    #pragma unroll
                    for (int j = 0; j < 8; ++j) v[j] = 0;
                }
                *(short8*)(sA1 + ((r * KB + half * 256 + c * 16) ^ ((r & 7) << 4))) = v;
            }
            if (half == 1) {
                short tv[16];
                #pragma unroll
                for (int j = 0; j < 16; ++j) tv[j] = 0;
                if (valid) {
                    #pragma unroll
                    for (int j = 0; j < EA_DIM; ++j) tv[j] = f2bf(ea[(size_t)e * EA_DIM + j]);
                }
                short8 v0, v1;
                #pragma unroll
                for (int j = 0; j < 8; ++j) { v0[j] = tv[j]; v1[j] = tv[8 + j]; }
                *(short8*)(sA1 + ((r * KB + 512) ^ ((r & 7) << 4))) = v0;
                *(short8*)(sA1 + ((r * KB + 528) ^ ((r & 7) << 4))) = v1;
                dsts[r] = valid ? idx : -1;
            }
        }
        __syncthreads();

        // ---- layer 1: acc1[mi][ni] over 17 K-steps ----
        f32x16 acc1[2][2] = {};
        int arow = mhalf * 64 + l31;
        int nrow = nhalf * 64 + l31;
        int koff = khalf * 16;
        for (int kk = 0; kk < 17; ++kk) {
            int kb = kk * 32 + koff;
            short8 a0 = *(short8*)(sA1 + (((arow)      * KB + kb) ^ ((arow & 7) << 4)));
            short8 a1 = *(short8*)(sA1 + (((arow + 32) * KB + kb) ^ ((arow & 7) << 4)));
            short8 w0 = *(short8*)(smem + (((nrow)      * KB + kb) ^ ((nrow & 7) << 4)));
            short8 w1 = *(short8*)(smem + (((nrow + 32) * KB + kb) ^ ((nrow & 7) << 4)));
            acc1[0][0] = __builtin_amdgcn_mfma_f32_32x32x16_bf16(a0, w0, acc1[0][0], 0, 0, 0);
            acc1[0][1] = __builtin_amdgcn_mfma_f32_32x32x16_bf16(a0, w1, acc1[0][1], 0, 0, 0);
            acc1[1][0] = __builtin_amdgcn_mfma_f32_32x32x16_bf16(a1, w0, acc1[1][0], 0, 0, 0);
            acc1[1][1] = __builtin_amdgcn_mfma_f32_32x32x16_bf16(a1, w1, acc1[1][1], 0, 0, 0);
        }

        __syncthreads();   // all layer-1 LDS reads done before overwriting A2 region

        // ---- bias + silu -> A2 (bf16, LDS, swizzled, 256B stride) ----
        #pragma unroll
        for (int mi = 0; mi < 2; ++mi)
            #pragma unroll
            for (int ni = 0; ni < 2; ++ni) {
                int colb = (nhalf * 64 + ni * 32 + l31) * 2;
                #pragma unroll
                for (int r = 0; r < 16; ++r) {
                    float s = siluf(acc1[mi][ni][r] + b1v[ni]);
                    int row = mhalf * 64 + mi * 32 + (r & 3) + 8 * (r >> 2) + 4 * khalf;
                    *(short*)(sA1 + ((row * 256 + colb) ^ ((row & 7) << 4))) = f2bf(s);
                }
            }
        __syncthreads();

        // ---- layer 2: acc2 = A2 @ W2 + b2 ; 8 K-steps; B from global (L1) ----
        f32x16 acc2[2][2];
        #pragma unroll
        for (int mi = 0; mi < 2; ++mi)
            #pragma unroll
            for (int ni = 0; ni < 2; ++ni)
                #pragma unroll
                for (int r = 0; r < 16; ++r) acc2[mi][ni][r] = b2v[ni];
        for (int kk = 0; kk < 8; ++kk) {
            int kb = kk * 32 + koff;
            short8 a0 = *(short8*)(sA1 + (((arow)      * 256 + kb) ^ ((arow & 7) << 4)));
            short8 a1 = *(short8*)(sA1 + (((arow + 32) * 256 + kb) ^ ((arow & 7) << 4)));
            short8 w0 = *(const short8*)(w2t + (size_t)(nrow)      * HID + kk * 16 + khalf * 8);
            short8 w1 = *(const short8*)(w2t + (size_t)(nrow + 32) * HID + kk * 16 + khalf * 8);
            acc2[0][0] = __builtin_amdgcn_mfma_f32_32x32x16_bf16(a0, w0, acc2[0][0], 0, 0, 0);
            acc2[0][1] = __builtin_amdgcn_mfma_f32_32x32x16_bf16(a0, w1, acc2[0][1], 0, 0, 0);
            acc2[1][0] = __builtin_amdgcn_mfma_f32_32x32x16_bf16(a1, w0, acc2[1][0], 0, 0, 0);
            acc2[1][1] = __builtin_amdgcn_mfma_f32_32x32x16_bf16(a1, w1, acc2[1][1], 0, 0, 0);
        }

        // ---- atomic scatter into agg[dst] ----
        #pragma unroll
        for (int mi = 0; mi < 2; ++mi)
            #pragma unroll
            for (int ni = 0; ni < 2; ++ni) {
                int col = nhalf * 64 + ni * 32 + l31;
                #pragma unroll
                for (int r = 0; r < 16; ++r) {
                    int lrow = mhalf * 64 + mi * 32 + (r & 3) + 8 * (r >> 2) + 4 * khalf;
                    int d = dsts[lrow];
                    if (d >= 0) atomicAdd(agg + (size_t)d * HID + col, acc2[mi][ni][r]);
                }
            }
    }
}

// ---------------- update: h = silu(concat(h,agg)@W + b + h), G nodes/block ----------------
__global__ __launch_bounds__(128) void upd_kernel(
    float* __restrict__ h, const float* __restrict__ agg,
    const float* __restrict__ W, const float* __restrict__ b, int N)
{
    int j = threadIdx.x;
    int base = blockIdx.x * G;
    __shared__ float inp[G][2 * HID];
    float hj[G];
    #pragma unroll
    for (int g = 0; g < G; ++g) {
        int i = base + g;
        hj[g] = 0.f;
        if (i < N) {
            hj[g] = h[(size_t)i * HID + j];
            inp[g][j]       = hj[g];
            inp[g][HID + j] = agg[(size_t)i * HID + j];
        }
    }
    __syncthreads();
    float bj = b[j];
    float acc[G];
    #pragma unroll
    for (int g = 0; g < G; ++g) acc[g] = bj + hj[g];
    #pragma unroll 4
    for (int k = 0; k < 2 * HID; ++k) {
        float w = W[k * HID + j];
        #pragma unroll
        for (int g = 0; g < G; ++g) acc[g] = fmaf(inp[g][k], w, acc[g]);
    }
    #pragma unroll
    for (int g = 0; g < G; ++g) {
        int i = base + g;
        if (i < N) h[(size_t)i * HID + j] = siluf(acc[g]);
    }
}

// ---------------- edge fields decoder ----------------
__global__ __launch_bounds__(64) void fields_kernel(
    const float* __restrict__ h, const int* __restrict__ conn,
    const float* __restrict__ bc,
    const float* __restrict__ W1, const float* __restrict__ b1,
    const float* __restrict__ W2, const float* __restrict__ b2,
    const float* __restrict__ W3, const float* __restrict__ b3,
    float* __restrict__ xi_out, float* __restrict__ f_out, int nq)
{
    int ec = blockIdx.x, j = threadIdx.x;   // 64 threads = 1 wave
    int n1 = conn[(size_t)ec * 2 + 0];
    int n2 = conn[(size_t)ec * 2 + 1];
    __shared__ float hs[2 * HID];
    __shared__ float ts[64];
    hs[j]       = h[(size_t)n1 * HID + j];
    hs[64 + j]  = h[(size_t)n1 * HID + 64 + j];
    hs[128 + j] = h[(size_t)n2 * HID + j];
    hs[192 + j] = h[(size_t)n2 * HID + 64 + j];
    __syncthreads();
    float hpart = b1[j];
    #pragma unroll 8
    for (int k = 0; k < 2 * HID; ++k) hpart = fmaf(hs[k], W1[(k + 1) * 64 + j], hpart);
    float w1x = W1[j];
    float bci = bc[n1], bcj = bc[n2];
    float b30 = b3[0], b31 = b3[1], b32 = b3[2];
    float w30 = W3[j * 3 + 0], w31 = W3[j * 3 + 1], w32 = W3[j * 3 + 2];
    float inv = (nq > 1) ? 1.f / (float)(nq - 1) : 0.f;
    for (int q = 0; q < nq; ++q) {
        float xi = (float)q * inv;
        float f1 = siluf(fmaf(xi, w1x, hpart));
        __syncthreads();
        ts[j] = f1;
        __syncthreads();
        float f2 = b2[j];
        #pragma unroll 8
        for (int k = 0; k < 64; ++k) f2 = fmaf(ts[k], W2[k * 64 + j], f2);
        f2 = siluf(f2);
        float p0 = f2 * w30, p1 = f2 * w31, p2 = f2 * w32;
        #pragma unroll
        for (int off = 32; off > 0; off >>= 1) {
            p0 += __shfl_down(p0, off);
            p1 += __shfl_down(p1, off);
            p2 += __shfl_down(p2, off);
        }
        if (j == 0) {
            float mask = (1.f - bci * (1.f - xi)) * (1.f - bcj * xi);
            size_t base = ((size_t)ec * nq + q) * 3;
            f_out[base + 0] = (p0 + b30) * mask;
            f_out[base + 1] = (p1 + b31) * mask;
            f_out[base + 2] = (p2 + b32) * mask;
            xi_out[(size_t)ec * nq + q] = xi;
        }
    }
}

__global__ void prop_kernel(const float* __restrict__ prop, float* __restrict__ out_p, int n)
{
    int i = blockIdx.x * blockDim.x + threadIdx.x;
    if (i < n) out_p[i] = prop[i];
}

extern "C" void kernel_launch(void* const* d_in, const int* in_sizes, int n_in,
                              void* d_out, int out_size, void* d_ws, size_t ws_size,
                              hipStream_t stream) {
    const float* x     = (const float*)d_in[0];
    const int*   ei    = (const int*)d_in[1];
    const float* ea    = (const float*)d_in[2];
    const int*   conn  = (const int*)d_in[3];
    const float* bc    = (const float*)d_in[4];
    const float* prop  = (const float*)d_in[5];
    const float* encW1 = (const float*)d_in[7];
    const float* encb1 = (const float*)d_in[8];
    const float* encW2 = (const float*)d_in[9];
    const float* encb2 = (const float*)d_in[10];
    const float* msgW1 = (const float*)d_in[11];
    const float* msgb1 = (const float*)d_in[12];
    const float* msgW2 = (const float*)d_in[13];
    const float* msgb2 = (const float*)d_in[14];
    const float* updW  = (const float*)d_in[15];
    const float* updb  = (const float*)d_in[16];
    const float* efW1  = (const float*)d_in[17];
    const float* efb1  = (const float*)d_in[18];
    const float* efW2  = (const float*)d_in[19];
    const float* efb2  = (const float*)d_in[20];
    const float* efW3  = (const float*)d_in[21];
    const float* efb3  = (const float*)d_in[22];

    int N  = in_sizes[0] / 9;
    int E  = in_sizes[1] / 2;
    int EC = in_sizes[5];
    int nl = in_sizes[11] / (MSG_IN * HID);
    int nq = (int)(((long long)out_size - (long long)N * HID - EC) / (4LL * EC));

    float* out    = (float*)d_out;
    float* h      = out;                       // h state lives in the output's h region
    float* out_xi = out + (size_t)N * HID;
    float* out_f  = out_xi + (size_t)EC * nq;
    float* out_p  = out_f + (size_t)EC * nq * 3;

    // ws layout: [w1t bf16 nl*128*KCAP][w2t bf16 nl*128*128][agg fp32 N*HID]
    short* w1t = (short*)d_ws;
    size_t w1t_elems = (size_t)nl * 128 * KCAP;
    short* w2t = w1t + w1t_elems;
    size_t w2t_elems = (size_t)nl * 128 * HID;
    float* agg = (float*)(w2t + w2t_elems);

    hipFuncSetAttribute((const void*)msg_mfma_kernel,
                        hipFuncAttributeMaxDynamicSharedMemorySize, LDS_TOTAL);

    encoder_kernel<<<N, 128, 0, stream>>>(x, encW1, encb1, encW2, encb2, h);

    {
        int chunks = nl * 128 * (KCAP / 8) + nl * 128 * (HID / 8);
        convert_w_kernel<<<(chunks + 255) / 256, 256, 0, stream>>>(msgW1, msgW2, w1t, w2t, nl);
    }

    int ntiles = (E + TILE_E - 1) / TILE_E;
    for (int l = 0; l < nl; ++l) {
        hipMemsetAsync(agg, 0, (size_t)N * HID * sizeof(float), stream);
        msg_mfma_kernel<<<256, 256, LDS_TOTAL, stream>>>(
            h, ei, ea,
            w1t + (size_t)l * 128 * KCAP, msgb1 + (size_t)l * HID,
            w2t + (size_t)l * 128 * HID,  msgb2 + (size_t)l * HID,
            agg, E, ntiles);
        upd_kernel<<<(N + G - 1) / G, 128, 0, stream>>>(
            h, agg, updW + (size_t)l * 2 * HID * HID, updb + (size_t)l * HID, N);
    }

    fields_kernel<<<EC, 64, 0, stream>>>(h, conn, bc, efW1, efb1, efW2, efb2, efW3, efb3,
                                         out_xi, out_f, nq);

    prop_kernel<<<(EC + 255) / 256, 256, 0, stream>>>(prop, out_p, EC);
}

// Round 4
// 2751.241 us; speedup vs baseline: 4.1494x; 1.2470x over previous
//
#include <hip/hip_runtime.h>
#include <hip/hip_bf16.h>

#define HID 128
#define EA_DIM 11
#define MSG_IN (2 * HID + EA_DIM)   // 267
#define TILE_E 128
#define KCAP 272                     // layer-1 K padded to 17*16
#define KB (KCAP * 2)                // 544 bytes per LDS row
#define LDS_A1 69632                 // W1T occupies [0, 69632)
#define LDS_TOTAL 139264

typedef __attribute__((ext_vector_type(8))) short short8;
typedef __attribute__((ext_vector_type(16))) float f32x16;
typedef __attribute__((ext_vector_type(4))) float float4v;

__device__ __forceinline__ float siluf(float x) { return x / (1.f + __expf(-x)); }
__device__ __forceinline__ short f2bf(float f) {
    __hip_bfloat16 h = __float2bfloat16(f);
    return *reinterpret_cast<short*>(&h);
}
__device__ __forceinline__ int crow(int r, int khalf) { return (r & 3) + 8 * (r >> 2) + 4 * khalf; }

// ---------------- encoder: h = silu(silu(x@W1+b1)@W2+b2); writes fp32 h + bf16 hb ----
__global__ __launch_bounds__(128) void encoder_kernel(
    const float* __restrict__ x, const float* __restrict__ W1, const float* __restrict__ b1,
    const float* __restrict__ W2, const float* __restrict__ b2,
    float* __restrict__ h, short* __restrict__ hb)
{
    int i = blockIdx.x, j = threadIdx.x;
    __shared__ float xs[9];
    __shared__ float t1[HID];
    if (j < 9) xs[j] = x[(size_t)i * 9 + j];
    __syncthreads();
    float acc = b1[j];
    #pragma unroll
    for (int k = 0; k < 9; ++k) acc = fmaf(xs[k], W1[k * HID + j], acc);
    t1[j] = siluf(acc);
    __syncthreads();
    float acc2 = b2[j];
    #pragma unroll 8
    for (int k = 0; k < HID; ++k) acc2 = fmaf(t1[k], W2[k * HID + j], acc2);
    float v = siluf(acc2);
    h[(size_t)i * HID + j] = v;
    if (hb) hb[(size_t)i * HID + j] = f2bf(v);
}

// ---- one-time weight conversion to transposed bf16 layouts ----
__global__ void convert_w_kernel(
    const float* __restrict__ msgW1, const float* __restrict__ msgW2,
    const float* __restrict__ updW,
    const float* __restrict__ efW1, const float* __restrict__ efW2, const float* __restrict__ efW3,
    short* __restrict__ w1t, short* __restrict__ w2t, short* __restrict__ updwt,
    short* __restrict__ efw1t, short* __restrict__ efw2t, short* __restrict__ efw3t, int nl)
{
    int gid = blockIdx.x * blockDim.x + threadIdx.x;
    int n1 = nl * 128 * (KCAP / 8);
    int n2 = nl * 128 * (HID / 8);
    int n3 = nl * 128 * 32;
    int n4 = 64 * 32, n5 = 64 * 8, n6 = 32 * 8;
    short8 v;
    if (gid < n1) {
        int c = gid % (KCAP / 8);
        int rem = gid / (KCAP / 8);
        int n = rem % 128, lay = rem / 128;
        #pragma unroll
        for (int j = 0; j < 8; ++j) {
            int k = c * 8 + j;
            v[j] = (k < MSG_IN) ? f2bf(msgW1[(size_t)lay * MSG_IN * HID + (size_t)k * HID + n]) : (short)0;
        }
        *(short8*)(w1t + ((size_t)lay * 128 + n) * KCAP + c * 8) = v;
    } else if (gid < n1 + n2) {
        int g = gid - n1;
        int c = g % (HID / 8);
        int rem = g / (HID / 8);
        int n = rem % 128, lay = rem / 128;
        #pragma unroll
        for (int j = 0; j < 8; ++j)
            v[j] = f2bf(msgW2[(size_t)lay * HID * HID + (size_t)(c * 8 + j) * HID + n]);
        *(short8*)(w2t + ((size_t)lay * 128 + n) * HID + c * 8) = v;
    } else if (gid < n1 + n2 + n3) {
        int g = gid - n1 - n2;
        int c = g & 31;
        int rem = g >> 5;
        int n = rem & 127, lay = rem >> 7;
        #pragma unroll
        for (int j = 0; j < 8; ++j)
            v[j] = f2bf(updW[(size_t)lay * 256 * 128 + (size_t)(c * 8 + j) * 128 + n]);
        *(short8*)(updwt + ((size_t)lay * 128 + n) * 256 + c * 8) = v;
    } else if (gid < n1 + n2 + n3 + n4) {
        int g = gid - n1 - n2 - n3;
        int c = g & 31, n = g >> 5;
        #pragma unroll
        for (int j = 0; j < 8; ++j)
            v[j] = f2bf(efW1[(size_t)(c * 8 + j + 1) * 64 + n]);
        *(short8*)(efw1t + (size_t)n * 256 + c * 8) = v;
    } else if (gid < n1 + n2 + n3 + n4 + n5) {
        int g = gid - n1 - n2 - n3 - n4;
        int c = g & 7, n = g >> 3;
        #pragma unroll
        for (int j = 0; j < 8; ++j)
            v[j] = f2bf(efW2[(size_t)(c * 8 + j) * 64 + n]);
        *(short8*)(efw2t + (size_t)n * 64 + c * 8) = v;
    } else if (gid < n1 + n2 + n3 + n4 + n5 + n6) {
        int g = gid - n1 - n2 - n3 - n4 - n5;
        int c = g & 7, n = g >> 3;
        #pragma unroll
        for (int j = 0; j < 8; ++j)
            v[j] = (n < 3) ? f2bf(efW3[(size_t)(c * 8 + j) * 3 + n]) : (short)0;
        *(short8*)(efw3t + (size_t)n * 64 + c * 8) = v;
    }
}

// ---------------- MFMA message kernel ----------------
__global__ __launch_bounds__(256, 1) void msg_mfma_kernel(
    const float* __restrict__ h, const short* __restrict__ hb,
    const int* __restrict__ ei, const float* __restrict__ ea,
    const short* __restrict__ w1t, const float* __restrict__ b1,
    const short* __restrict__ w2t, const float* __restrict__ b2,
    float* __restrict__ agg, int E, int ntiles)
{
    extern __shared__ char smem[];          // [W1T 69632 | A1/A2 69632]
    char* sA1 = smem + LDS_A1;
    __shared__ int dsts[TILE_E];

    int tid = threadIdx.x;
    int ln = tid & 63;
    int wave = tid >> 6;
    int mhalf = wave & 1, nhalf = wave >> 1;
    int l31 = ln & 31, khalf = ln >> 5;

    // stage W1T once per block (swizzled)
    {
        int r = tid >> 1, half = tid & 1;
        #pragma unroll
        for (int c = 0; c < 17; ++c) {
            int cc = half * 17 + c;
            short8 v = *(const short8*)(w1t + (size_t)r * KCAP + cc * 8);
            *(short8*)(smem + ((r * KB + cc * 16) ^ ((r & 7) << 4))) = v;
        }
    }

    float b1v[2], b2v[2];
    #pragma unroll
    for (int ni = 0; ni < 2; ++ni) {
        b1v[ni] = b1[nhalf * 64 + ni * 32 + l31];
        b2v[ni] = b2[nhalf * 64 + ni * 32 + l31];
    }
    short8 zer;
    #pragma unroll
    for (int j = 0; j < 8; ++j) zer[j] = 0;

    #pragma unroll 1
    for (int tile = blockIdx.x; tile < ntiles; tile += gridDim.x) {
        __syncthreads();

        // ---- gather-stage A1 ----
        {
            int r = tid >> 1, half = tid & 1;
            long e = (long)tile * TILE_E + r;
            bool valid = e < E;
            int idx = 0;
            if (valid) idx = (half == 0) ? ei[e] : ei[(size_t)E + e];
            if (hb) {
                const short8* hr8 = (const short8*)(hb + (size_t)idx * HID);
                #pragma unroll 4
                for (int c = 0; c < 16; ++c) {
                    short8 v = valid ? hr8[c] : zer;
                    *(short8*)(sA1 + ((r * KB + half * 256 + c * 16) ^ ((r & 7) << 4))) = v;
                }
            } else {
                const float* hr = h + (size_t)idx * HID;
                #pragma unroll 4
                for (int c = 0; c < 16; ++c) {
                    short8 v = zer;
                    if (valid) {
                        float4v f0 = *(const float4v*)(hr + c * 8);
                        float4v f1 = *(const float4v*)(hr + c * 8 + 4);
                        #pragma unroll
                        for (int j = 0; j < 4; ++j) { v[j] = f2bf(f0[j]); v[4 + j] = f2bf(f1[j]); }
                    }
                    *(short8*)(sA1 + ((r * KB + half * 256 + c * 16) ^ ((r & 7) << 4))) = v;
                }
            }
            if (half == 1) {
                short tv[16];
                #pragma unroll
                for (int j = 0; j < 16; ++j) tv[j] = 0;
                if (valid) {
                    #pragma unroll
                    for (int j = 0; j < EA_DIM; ++j) tv[j] = f2bf(ea[(size_t)e * EA_DIM + j]);
                }
                short8 v0, v1;
                #pragma unroll
                for (int j = 0; j < 8; ++j) { v0[j] = tv[j]; v1[j] = tv[8 + j]; }
                *(short8*)(sA1 + ((r * KB + 512) ^ ((r & 7) << 4))) = v0;
                *(short8*)(sA1 + ((r * KB + 528) ^ ((r & 7) << 4))) = v1;
                dsts[r] = valid ? idx : -1;
            }
        }
        __syncthreads();

        // ---- layer 1 ----
        f32x16 acc1[2][2] = {};
        int arow = mhalf * 64 + l31;
        int nrow = nhalf * 64 + l31;
        int koff = khalf * 16;
        for (int kk = 0; kk < 17; ++kk) {
            int kb = kk * 32 + koff;
            short8 a0 = *(short8*)(sA1 + (((arow)      * KB + kb) ^ ((arow & 7) << 4)));
            short8 a1 = *(short8*)(sA1 + (((arow + 32) * KB + kb) ^ ((arow & 7) << 4)));
            short8 w0 = *(short8*)(smem + (((nrow)      * KB + kb) ^ ((nrow & 7) << 4)));
            short8 w1 = *(short8*)(smem + (((nrow + 32) * KB + kb) ^ ((nrow & 7) << 4)));
            acc1[0][0] = __builtin_amdgcn_mfma_f32_32x32x16_bf16(a0, w0, acc1[0][0], 0, 0, 0);
            acc1[0][1] = __builtin_amdgcn_mfma_f32_32x32x16_bf16(a0, w1, acc1[0][1], 0, 0, 0);
            acc1[1][0] = __builtin_amdgcn_mfma_f32_32x32x16_bf16(a1, w0, acc1[1][0], 0, 0, 0);
            acc1[1][1] = __builtin_amdgcn_mfma_f32_32x32x16_bf16(a1, w1, acc1[1][1], 0, 0, 0);
        }

        __syncthreads();

        // ---- bias + silu -> A2 ----
        #pragma unroll
        for (int mi = 0; mi < 2; ++mi)
            #pragma unroll
            for (int ni = 0; ni < 2; ++ni) {
                int colb = (nhalf * 64 + ni * 32 + l31) * 2;
                #pragma unroll
                for (int r = 0; r < 16; ++r) {
                    float s = siluf(acc1[mi][ni][r] + b1v[ni]);
                    int row = mhalf * 64 + mi * 32 + crow(r, khalf);
                    *(short*)(sA1 + ((row * 256 + colb) ^ ((row & 7) << 4))) = f2bf(s);
                }
            }
        __syncthreads();

        // ---- layer 2 ----
        f32x16 acc2[2][2];
        #pragma unroll
        for (int mi = 0; mi < 2; ++mi)
            #pragma unroll
            for (int ni = 0; ni < 2; ++ni)
                #pragma unroll
                for (int r = 0; r < 16; ++r) acc2[mi][ni][r] = b2v[ni];
        for (int kk = 0; kk < 8; ++kk) {
            int kb = kk * 32 + koff;
            short8 a0 = *(short8*)(sA1 + (((arow)      * 256 + kb) ^ ((arow & 7) << 4)));
            short8 a1 = *(short8*)(sA1 + (((arow + 32) * 256 + kb) ^ ((arow & 7) << 4)));
            short8 w0 = *(const short8*)(w2t + (size_t)(nrow)      * HID + kk * 16 + khalf * 8);
            short8 w1 = *(const short8*)(w2t + (size_t)(nrow + 32) * HID + kk * 16 + khalf * 8);
            acc2[0][0] = __builtin_amdgcn_mfma_f32_32x32x16_bf16(a0, w0, acc2[0][0], 0, 0, 0);
            acc2[0][1] = __builtin_amdgcn_mfma_f32_32x32x16_bf16(a0, w1, acc2[0][1], 0, 0, 0);
            acc2[1][0] = __builtin_amdgcn_mfma_f32_32x32x16_bf16(a1, w0, acc2[1][0], 0, 0, 0);
            acc2[1][1] = __builtin_amdgcn_mfma_f32_32x32x16_bf16(a1, w1, acc2[1][1], 0, 0, 0);
        }

        // ---- atomic scatter ----
        #pragma unroll
        for (int mi = 0; mi < 2; ++mi)
            #pragma unroll
            for (int ni = 0; ni < 2; ++ni) {
                int col = nhalf * 64 + ni * 32 + l31;
                #pragma unroll
                for (int r = 0; r < 16; ++r) {
                    int lrow = mhalf * 64 + mi * 32 + crow(r, khalf);
                    int d = dsts[lrow];
                    if (d >= 0) atomicAdd(agg + (size_t)d * HID + col, acc2[mi][ni][r]);
                }
            }
    }
}

// ---------------- MFMA update kernel: h = silu([h|agg]@W + b + h) ----------------
__global__ __launch_bounds__(256) void upd_mfma_kernel(
    float* __restrict__ h, short* __restrict__ hb, const float* __restrict__ agg,
    const short* __restrict__ updwt, const float* __restrict__ b, int N, int ntiles)
{
    __shared__ char sA[64 * 512];
    int tid = threadIdx.x, ln = tid & 63, wave = tid >> 6;
    int mhalf = wave & 1, nhalf = wave >> 1, l31 = ln & 31, khalf = ln >> 5;
    float bv[2];
    #pragma unroll
    for (int ni = 0; ni < 2; ++ni) bv[ni] = b[nhalf * 64 + ni * 32 + l31];
    short8 zer;
    #pragma unroll
    for (int j = 0; j < 8; ++j) zer[j] = 0;

    #pragma unroll 1
    for (int tile = blockIdx.x; tile < ntiles; tile += gridDim.x) {
        __syncthreads();
        {
            int r = tid >> 2, q = tid & 3;
            int node = tile * 64 + r;
            bool valid = node < N;
            if (q < 2) {
                if (hb) {
                    const short8* hr8 = (const short8*)(hb + (size_t)node * HID + (q & 1) * 64);
                    #pragma unroll
                    for (int c = 0; c < 8; ++c) {
                        short8 v = valid ? hr8[c] : zer;
                        *(short8*)(sA + ((r * 512 + (q & 1) * 128 + c * 16) ^ ((r & 7) << 4))) = v;
                    }
                } else {
                    const float* hr = h + (size_t)node * HID + (q & 1) * 64;
                    #pragma unroll
                    for (int c = 0; c < 8; ++c) {
                        short8 v = zer;
                        if (valid) {
                            float4v f0 = *(const float4v*)(hr + c * 8);
                            float4v f1 = *(const float4v*)(hr + c * 8 + 4);
                            #pragma unroll
                            for (int j = 0; j < 4; ++j) { v[j] = f2bf(f0[j]); v[4 + j] = f2bf(f1[j]); }
                        }
                        *(short8*)(sA + ((r * 512 + (q & 1) * 128 + c * 16) ^ ((r & 7) << 4))) = v;
                    }
                }
            } else {
                const float* ar = agg + (size_t)node * HID + (q & 1) * 64;
                #pragma unroll
                for (int c = 0; c < 8; ++c) {
                    short8 v = zer;
                    if (valid) {
                        float4v f0 = *(const float4v*)(ar + c * 8);
                        float4v f1 = *(const float4v*)(ar + c * 8 + 4);
                        #pragma unroll
                        for (int j = 0; j < 4; ++j) { v[j] = f2bf(f0[j]); v[4 + j] = f2bf(f1[j]); }
                    }
                    *(short8*)(sA + ((r * 512 + 256 + (q & 1) * 128 + c * 16) ^ ((r & 7) << 4))) = v;
                }
            }
        }
        __syncthreads();

        f32x16 acc[2] = {};
        int arow = mhalf * 32 + l31;
        const short* bp0 = updwt + (size_t)(nhalf * 64 + l31) * 256 + khalf * 8;
        const short* bp1 = updwt + (size_t)(nhalf * 64 + 32 + l31) * 256 + khalf * 8;
        for (int kk = 0; kk < 16; ++kk) {
            short8 a  = *(short8*)(sA + ((arow * 512 + kk * 32 + khalf * 16) ^ ((arow & 7) << 4)));
            short8 w0 = *(const short8*)(bp0 + kk * 16);
            short8 w1 = *(const short8*)(bp1 + kk * 16);
            acc[0] = __builtin_amdgcn_mfma_f32_32x32x16_bf16(a, w0, acc[0], 0, 0, 0);
            acc[1] = __builtin_amdgcn_mfma_f32_32x32x16_bf16(a, w1, acc[1], 0, 0, 0);
        }

        #pragma unroll
        for (int ni = 0; ni < 2; ++ni) {
            int col = nhalf * 64 + ni * 32 + l31;
            #pragma unroll
            for (int r = 0; r < 16; ++r) {
                int node = tile * 64 + mhalf * 32 + crow(r, khalf);
                if (node < N) {
                    float val = siluf(acc[ni][r] + bv[ni] + h[(size_t)node * HID + col]);
                    h[(size_t)node * HID + col] = val;
                    if (hb) hb[(size_t)node * HID + col] = f2bf(val);
                }
            }
        }
    }
}

// ---------------- MFMA edge-fields kernel ----------------
__global__ __launch_bounds__(256) void fields_mfma_kernel(
    const float* __restrict__ h, const short* __restrict__ hb,
    const int* __restrict__ conn, const float* __restrict__ bc,
    const float* __restrict__ efW1, const float* __restrict__ efb1,
    const float* __restrict__ efb2, const float* __restrict__ efb3,
    const short* __restrict__ efw1t, const short* __restrict__ efw2t, const short* __restrict__ efw3t,
    float* __restrict__ f_out, int EC, int nq, int ntiles)
{
    __shared__ char sA1[64 * 512];
    __shared__ char sA2[64 * 128];
    __shared__ char sF2[64 * 128];
    __shared__ float bcis[64], bcjs[64];
    int tid = threadIdx.x, ln = tid & 63, wave = tid >> 6;
    int mhalf = wave & 1, nhalf = wave >> 1, l31 = ln & 31, khalf = ln >> 5;
    int col = nhalf * 32 + l31;
    float w1x = efW1[col];
    float b1v = efb1[col], b2v = efb2[col];
    float b3v = (l31 < 3) ? efb3[l31] : 0.f;
    float inv = (nq > 1) ? 1.f / (float)(nq - 1) : 0.f;
    short8 zer;
    #pragma unroll
    for (int j = 0; j < 8; ++j) zer[j] = 0;

    #pragma unroll 1
    for (int tile = blockIdx.x; tile < ntiles; tile += gridDim.x) {
        __syncthreads();
        {
            int r = tid >> 2, q = tid & 3;
            long p = (long)tile * 64 + r;
            bool valid = p < EC;
            int node = 0;
            if (valid) node = conn[p * 2 + (q >> 1)];
            if (q == 0) {
                bcis[r] = valid ? bc[conn[p * 2]] : 0.f;
                bcjs[r] = valid ? bc[conn[p * 2 + 1]] : 0.f;
            }
            int cbyte = (q >> 1) * 256 + (q & 1) * 128;
            if (hb) {
                const short8* hr8 = (const short8*)(hb + (size_t)node * HID + (q & 1) * 64);
                #pragma unroll
                for (int c = 0; c < 8; ++c) {
                    short8 v = valid ? hr8[c] : zer;
                    *(short8*)(sA1 + ((r * 512 + cbyte + c * 16) ^ ((r & 7) << 4))) = v;
                }
            } else {
                const float* hr = h + (size_t)node * HID + (q & 1) * 64;
                #pragma unroll
                for (int c = 0; c < 8; ++c) {
                    short8 v = zer;
                    if (valid) {
                        float4v f0 = *(const float4v*)(hr + c * 8);
                        float4v f1 = *(const float4v*)(hr + c * 8 + 4);
                        #pragma unroll
                        for (int j = 0; j < 4; ++j) { v[j] = f2bf(f0[j]); v[4 + j] = f2bf(f1[j]); }
                    }
                    *(short8*)(sA1 + ((r * 512 + cbyte + c * 16) ^ ((r & 7) << 4))) = v;
                }
            }
        }
        __syncthreads();

        // GEMM1: hpart = [h_i|h_j] @ W1[1:] ; K=256
        f32x16 hp = {};
        int arow = mhalf * 32 + l31;
        for (int kk = 0; kk < 16; ++kk) {
            short8 a = *(short8*)(sA1 + ((arow * 512 + kk * 32 + khalf * 16) ^ ((arow & 7) << 4)));
            short8 b = *(const short8*)(efw1t + (size_t)col * 256 + kk * 16 + khalf * 8);
            hp = __builtin_amdgcn_mfma_f32_32x32x16_bf16(a, b, hp, 0, 0, 0);
        }
        #pragma unroll
        for (int r = 0; r < 16; ++r) hp[r] += b1v;

        for (int q = 0; q < nq; ++q) {
            float xi = (float)q * inv;
            #pragma unroll
            for (int r = 0; r < 16; ++r) {
                float f1 = siluf(fmaf(xi, w1x, hp[r]));
                int row = mhalf * 32 + crow(r, khalf);
                *(short*)(sA2 + ((row * 128 + col * 2) ^ ((row & 7) << 4))) = f2bf(f1);
            }
            __syncthreads();
            f32x16 f2a = {};
            for (int kk = 0; kk < 4; ++kk) {
                short8 a = *(short8*)(sA2 + ((arow * 128 + kk * 32 + khalf * 16) ^ ((l31 & 7) << 4)));
                short8 b = *(const short8*)(efw2t + (size_t)col * 64 + kk * 16 + khalf * 8);
                f2a = __builtin_amdgcn_mfma_f32_32x32x16_bf16(a, b, f2a, 0, 0, 0);
            }
            #pragma unroll
            for (int r = 0; r < 16; ++r) {
                float f2 = siluf(f2a[r] + b2v);
                int row = mhalf * 32 + crow(r, khalf);
                *(short*)(sF2 + ((row * 128 + col * 2) ^ ((row & 7) << 4))) = f2bf(f2);
            }
            __syncthreads();
            f32x16 oa = {};
            for (int kk = 0; kk < 4; ++kk) {
                short8 a = *(short8*)(sF2 + ((arow * 128 + kk * 32 + khalf * 16) ^ ((l31 & 7) << 4)));
                short8 b = *(const short8*)(efw3t + (size_t)l31 * 64 + kk * 16 + khalf * 8);
                oa = __builtin_amdgcn_mfma_f32_32x32x16_bf16(a, b, oa, 0, 0, 0);
            }
            if (nhalf == 0 && l31 < 3) {
                #pragma unroll
                for (int r = 0; r < 16; ++r) {
                    int row = mhalf * 32 + crow(r, khalf);
                    long p = (long)tile * 64 + row;
                    if (p < EC) {
                        float mask = (1.f - bcis[row] * (1.f - xi)) * (1.f - bcjs[row] * xi);
                        f_out[((size_t)p * nq + q) * 3 + l31] = (oa[r] + b3v) * mask;
                    }
                }
            }
        }
    }
}

// ---------------- aux: prop passthrough + xi fill ----------------
__global__ void aux_kernel(const float* __restrict__ prop, float* __restrict__ out_p,
                           float* __restrict__ out_xi, int EC, int nq, float inv)
{
    int i = blockIdx.x * blockDim.x + threadIdx.x;
    if (i < EC) out_p[i] = prop[i];
    if (i < EC * nq) out_xi[i] = (float)(i % nq) * inv;
}

extern "C" void kernel_launch(void* const* d_in, const int* in_sizes, int n_in,
                              void* d_out, int out_size, void* d_ws, size_t ws_size,
                              hipStream_t stream) {
    const float* x     = (const float*)d_in[0];
    const int*   ei    = (const int*)d_in[1];
    const float* ea    = (const float*)d_in[2];
    const int*   conn  = (const int*)d_in[3];
    const float* bc    = (const float*)d_in[4];
    const float* prop  = (const float*)d_in[5];
    const float* encW1 = (const float*)d_in[7];
    const float* encb1 = (const float*)d_in[8];
    const float* encW2 = (const float*)d_in[9];
    const float* encb2 = (const float*)d_in[10];
    const float* msgW1 = (const float*)d_in[11];
    const float* msgb1 = (const float*)d_in[12];
    const float* msgW2 = (const float*)d_in[13];
    const float* msgb2 = (const float*)d_in[14];
    const float* updW  = (const float*)d_in[15];
    const float* updb  = (const float*)d_in[16];
    const float* efW1  = (const float*)d_in[17];
    const float* efb1  = (const float*)d_in[18];
    const float* efW2  = (const float*)d_in[19];
    const float* efb2  = (const float*)d_in[20];
    const float* efW3  = (const float*)d_in[21];
    const float* efb3  = (const float*)d_in[22];

    int N  = in_sizes[0] / 9;
    int E  = in_sizes[1] / 2;
    int EC = in_sizes[5];
    int nl = in_sizes[11] / (MSG_IN * HID);
    int nq = (int)(((long long)out_size - (long long)N * HID - EC) / (4LL * EC));

    float* out    = (float*)d_out;
    float* h      = out;
    float* out_xi = out + (size_t)N * HID;
    float* out_f  = out_xi + (size_t)EC * nq;
    float* out_p  = out_f + (size_t)EC * nq * 3;

    // ws layout: [w1t][w2t][updwt][efw1t][efw2t][efw3t] [hb] [agg]
    size_t w1t_e = (size_t)nl * 128 * KCAP;
    size_t w2t_e = (size_t)nl * 128 * HID;
    size_t updwt_e = (size_t)nl * 128 * 256;
    size_t efw1t_e = 64 * 256, efw2t_e = 64 * 64, efw3t_e = 32 * 64;
    short* w1t   = (short*)d_ws;
    short* w2t   = w1t + w1t_e;
    short* updwt = w2t + w2t_e;
    short* efw1t = updwt + updwt_e;
    short* efw2t = efw1t + efw1t_e;
    short* efw3t = efw2t + efw2t_e;
    size_t wbytes = (w1t_e + w2t_e + updwt_e + efw1t_e + efw2t_e + efw3t_e) * 2;
    wbytes = (wbytes + 255) & ~(size_t)255;
    size_t hb_bytes = (size_t)N * HID * 2;
    size_t agg_bytes = (size_t)N * HID * 4;
    short* hb;
    float* agg;
    if (ws_size >= wbytes + hb_bytes + agg_bytes) {
        hb  = (short*)((char*)d_ws + wbytes);
        agg = (float*)((char*)d_ws + wbytes + hb_bytes);
    } else {
        hb  = nullptr;
        agg = (float*)((char*)d_ws + wbytes);
    }

    hipFuncSetAttribute((const void*)msg_mfma_kernel,
                        hipFuncAttributeMaxDynamicSharedMemorySize, LDS_TOTAL);

    encoder_kernel<<<N, 128, 0, stream>>>(x, encW1, encb1, encW2, encb2, h, hb);

    {
        int chunks = nl * 128 * (KCAP / 8) + nl * 128 * (HID / 8) + nl * 128 * 32
                   + 64 * 32 + 64 * 8 + 32 * 8;
        convert_w_kernel<<<(chunks + 255) / 256, 256, 0, stream>>>(
            msgW1, msgW2, updW, efW1, efW2, efW3,
            w1t, w2t, updwt, efw1t, efw2t, efw3t, nl);
    }

    int ntiles = (E + TILE_E - 1) / TILE_E;
    int utiles = (N + 63) / 64;
    for (int l = 0; l < nl; ++l) {
        hipMemsetAsync(agg, 0, agg_bytes, stream);
        msg_mfma_kernel<<<256, 256, LDS_TOTAL, stream>>>(
            h, hb, ei, ea,
            w1t + (size_t)l * 128 * KCAP, msgb1 + (size_t)l * HID,
            w2t + (size_t)l * 128 * HID,  msgb2 + (size_t)l * HID,
            agg, E, ntiles);
        upd_mfma_kernel<<<512, 256, 0, stream>>>(
            h, hb, agg, updwt + (size_t)l * 128 * 256, updb + (size_t)l * HID, N, utiles);
    }

    int ftiles = (EC + 63) / 64;
    fields_mfma_kernel<<<512, 256, 0, stream>>>(
        h, hb, conn, bc, efW1, efb1, efb2, efb3, efw1t, efw2t, efw3t,
        out_f, EC, nq, ftiles);

    float inv = (nq > 1) ? 1.f / (float)(nq - 1) : 0.f;
    aux_kernel<<<(EC * nq + 255) / 256, 256, 0, stream>>>(prop, out_p, out_xi, EC, nq, inv);
}